// Round 5
// baseline (506.533 us; speedup 1.0000x reference)
//
#include <hip/hip_runtime.h>

#define CURV 2.3026f
#define EPSF 1e-15f

typedef __attribute__((ext_vector_type(8))) short bfrag8;
typedef __attribute__((ext_vector_type(4))) float ffrag4;

static __device__ __forceinline__ unsigned short f2bf(float f) {
  unsigned u = __builtin_bit_cast(unsigned, f);
  u += 0x7fffu + ((u >> 16) & 1u);
  return (unsigned short)(u >> 16);
}

// async global->LDS, 16B per lane; LDS dest = wave-uniform base + lane*16 (global side is per-lane)
static __device__ __forceinline__ void gld16(const void* g, void* l) {
  unsigned lo = (unsigned)(unsigned long long)l;
  __builtin_amdgcn_global_load_lds(
      (const __attribute__((address_space(1))) unsigned int*)g,
      (__attribute__((address_space(3))) unsigned int*)lo, 16, 0, 0);
}

// ---- weight prep, coalesced: LDS-tiled 64x64 transpose + per-col stats ----
// grid: blocks 0..7 = L1 (768x512), 8..11 = L2 (512x256), 12..13 = L3 (256x128), 14 = L4 (128x1)
__global__ void prep_tiled(const float* __restrict__ z1, const float* __restrict__ r1,
                           const float* __restrict__ z2, const float* __restrict__ r2,
                           const float* __restrict__ z3, const float* __restrict__ r3,
                           const float* __restrict__ z4, const float* __restrict__ r4,
                           unsigned short* __restrict__ zT1, float* __restrict__ st1,
                           unsigned short* __restrict__ zT2, float* __restrict__ st2,
                           unsigned short* __restrict__ zT3, float* __restrict__ st3,
                           unsigned short* __restrict__ zT4, float* __restrict__ st4) {
  int b = blockIdx.x, t = threadIdx.x;  // 256 threads
  const float *z, *rv; unsigned short* zT; float* st; int K, N, nt;
  if (b < 8)       { z = z1; rv = r1; zT = zT1; st = st1; K = 768; N = 512; nt = b; }
  else if (b < 12) { z = z2; rv = r2; zT = zT2; st = st2; K = 512; N = 256; nt = b - 8; }
  else if (b < 14) { z = z3; rv = r3; zT = zT3; st = st3; K = 256; N = 128; nt = b - 12; }
  else             { z = z4; rv = r4; zT = zT4; st = st4; K = 128; N = 1;   nt = 0; }
  const float cs = sqrtf(CURV);
  if (N == 1) {  // contiguous column: trivial
    float v = (t < K) ? z[t] : 0.f;
    if (t < K) zT[t] = f2bf(v);
    float ssl = v * v;
    __shared__ float red4[4];
    for (int m = 1; m <= 32; m <<= 1) ssl += __shfl_xor(ssl, m);
    if ((t & 63) == 0) red4[t >> 6] = ssl;
    __syncthreads();
    if (t == 0) {
      float ss = red4[0] + red4[1] + red4[2] + red4[3];
      float zn = fmaxf(sqrtf(ss), EPSF);
      float tc = 2.f * cs * rv[0];
      st[0] = 2.f * (zn - 1.f); st[1] = coshf(tc) / zn; st[2] = sinhf(tc); st[3] = 0.f;
    }
    return;
  }
  __shared__ unsigned short tile[64 * 72];  // stride 72 (144B, 16B-aligned)
  __shared__ float red[4][64];
  const int c = t & 63, rq = t >> 6;
  const int n0 = nt * 64;
  float ssl = 0.f;
  for (int kk = 0; kk < K; kk += 64) {
#pragma unroll
    for (int p = 0; p < 16; p++) {
      int k = kk + 4 * p + rq;
      float v = z[(size_t)k * N + n0 + c];  // 64 consecutive cols: coalesced
      ssl += v * v;
      tile[c * 72 + 4 * p + rq] = f2bf(v);  // transposed store
    }
    __syncthreads();
    // write 64 rows x 128B coalesced; thread: row = t>>2, 32B segment = t&3 (16 shorts each)
    {
      int wr = t >> 2, seg = t & 3;
      const unsigned long long* src = (const unsigned long long*)(tile + wr * 72 + seg * 16);
      unsigned long long* dst = (unsigned long long*)(zT + (size_t)(n0 + wr) * K + kk + seg * 16);
      dst[0] = src[0]; dst[1] = src[1]; dst[2] = src[2]; dst[3] = src[3];
    }
    __syncthreads();
  }
  red[rq][c] = ssl; __syncthreads();
  if (t < 64) {
    float ss = red[0][t] + red[1][t] + red[2][t] + red[3][t];
    float zn = fmaxf(sqrtf(ss), EPSF);
    float tc = 2.f * cs * rv[n0 + t];
    st[4 * (n0 + t) + 0] = 2.f * (zn - 1.f);
    st[4 * (n0 + t) + 1] = coshf(tc) / zn;
    st[4 * (n0 + t) + 2] = sinhf(tc);
    st[4 * (n0 + t) + 3] = 0.f;
  }
}

// s -> w via polynomial sinh(2*zn*asinh(g)) expansion (|g|<~0.35, |delta|<~0.16); in place on acc
template<int NT>
static __device__ __forceinline__ void poly_w(ffrag4 (&acc)[2][NT], const float* __restrict__ stats,
                                              int wn, int lm, int wm, int quad,
                                              const float* lamP, float cs, float inv_cs) {
#pragma unroll
  for (int tn = 0; tn < NT; tn++) {
    float4 st = *(const float4*)(stats + 4 * (wn * (16 * NT) + 16 * tn + lm));
    float dl = st.x, chozn = st.y, sh = st.z;
#pragma unroll
    for (int tm = 0; tm < 2; tm++) {
#pragma unroll
      for (int rg = 0; rg < 4; rg++) {
        float lam = lamP[32 * wm + 16 * tm + 4 * quad + rg];
        float g = cs * lam * acc[tm][tn][rg] * chozn - (lam - 1.f) * sh;
        float q = g * g;
        float u = g * (1.f - q * (1.f / 6.f) + q * q * 0.075f - q * q * q * 0.044642857f);
        float d1 = dl * u;
        float S = 2.f * g * sqrtf(1.f + q);
        float Ch = 1.f + 2.f * q;
        acc[tm][tn][rg] = (S * (1.f + 0.5f * d1 * d1) + Ch * d1) * inv_cs;
      }
    }
  }
}

// row reductions: sum w^2, sum relu(w)^2, (L4) sum relu(w)*z4
template<int NT, bool L4>
static __device__ __forceinline__ void reduce_rows(ffrag4 (&acc)[2][NT], const float* z4v,
                                                   int lm, int wm, int quad, float (*sums_)[64]) {
#pragma unroll
  for (int tm = 0; tm < 2; tm++) {
#pragma unroll
    for (int rg = 0; rg < 4; rg++) {
      float s2 = 0.f, sp2 = 0.f, s4 = 0.f;
#pragma unroll
      for (int tn = 0; tn < NT; tn++) {
        float w = acc[tm][tn][rg];
        s2 += w * w;
        float wp = fmaxf(w, 0.f);
        sp2 += wp * wp;
        if (L4) s4 += wp * z4v[tn];
      }
#pragma unroll
      for (int m = 1; m <= 8; m <<= 1) {
        s2 += __shfl_xor(s2, m, 16);
        sp2 += __shfl_xor(sp2, m, 16);
        if (L4) s4 += __shfl_xor(s4, m, 16);
      }
      if (lm == 0) {
        int row = 32 * wm + 16 * tm + 4 * quad + rg;
        atomicAdd(&sums_[0][row], s2);
        atomicAdd(&sums_[1][row], sp2);
        if (L4) atomicAdd(&sums_[2][row], s4);
      }
    }
  }
}

// write h = gam*relu(w) as bf16 into a panel of 4KB k-tiles in the paired-row swizzled layout:
// data (row r, 16B-chunk c' in [0,4)) of k-tile kt at kt*4096 + (r>>1)*128 + ((4*(r&1)+c')^((r>>1)&7))*16
template<int NT>
static __device__ __forceinline__ void panel_write(ffrag4 (&acc)[2][NT], char* panel,
                                                   int lm, int wm, int wn, int quad,
                                                   const float* gamP) {
#pragma unroll
  for (int tm = 0; tm < 2; tm++)
#pragma unroll
    for (int rg = 0; rg < 4; rg++) {
      const int r = 32 * wm + 16 * tm + 4 * quad + rg;
      const float gam = gamP[r];
      const unsigned rb = (unsigned)((r >> 1) * 128);
      const unsigned rx = (unsigned)((r >> 1) & 7);
      const unsigned c0 = (unsigned)((r & 1) * 4);
#pragma unroll
      for (int tn = 0; tn < NT; tn++) {
        const int col = wn * (16 * NT) + 16 * tn + lm;
        const unsigned ad = (unsigned)((col >> 5) * 4096) + rb +
                            (((c0 + (unsigned)((col >> 3) & 3)) ^ rx) << 4) +
                            (unsigned)((col & 7) * 2);
        *(unsigned short*)(panel + ad) = f2bf(gam * fmaxf(acc[tm][tn][rg], 0.f));
      }
    }
}

// convert 2 fp32 -> 2 bf16, ds_write_b32 into paired-row layout; returns sum of squares
static __device__ __forceinline__ float stage_a2(float2 f, char* p) {
  unsigned lo = f2bf(f.x), hi = f2bf(f.y);
  *(unsigned*)p = lo | (hi << 16);
  return f.x * f.x + f.y * f.y;
}

// ---- fully fused 4-layer Poincare MLP: 64 rows/block, 16 waves (2M x 8N).
// Phase 1: BK=32, A reg-staged (fp32->bf16 once, ds_write_b32, ss in-flight), B1 via gld16, dbuf.
// Phases 2/3: A-frags from persistent LDS h-panels; B-frags STREAMED per k-step from L2-warm
// global (zT2=256KB, zT3=64KB) -> ZERO barriers in the k-loops, no B LDS, no B register panel.
// LDS 72KB (+1.3KB) + <=64 VGPR (launch_bounds 1024,8) -> 2 blocks/CU, 32 waves resident:
// each block's barrier drains overlap with the other block's compute.
//   ph1: A1 dbuf [0,8K) + B1 dbuf [8K,72K);  ph2: H1 [0,64K);  ph3: H2 [0,32K)
__launch_bounds__(1024, 8)
__global__ void fused_mlp(const float* __restrict__ x,
                          const unsigned short* __restrict__ zt1, const float* __restrict__ st1,
                          const unsigned short* __restrict__ zt2, const float* __restrict__ st2,
                          const unsigned short* __restrict__ zt3, const float* __restrict__ st3,
                          const float* __restrict__ z4, const float* __restrict__ st4,
                          float* __restrict__ outF) {
  __shared__ __align__(16) char smem[73728];
  __shared__ float lamS[64];
  __shared__ float gamS[64];
  __shared__ float sums[3][64];

  const int t = threadIdx.x;
  const int wid = t >> 6, lane = t & 63;
  const int wm = wid >> 3, wn = wid & 7;
  const int lm = lane & 15, quad = lane >> 4;
  const int l7 = lane & 7, rl8 = lane >> 3;
  const unsigned rowg0 = blockIdx.x * 64u;

  char* const A1 = smem;          // 2 x 4KB bf16 x-tiles (64 rows x 32 k)
  char* const B1 = smem + 8192;   // 2 x 32KB (512 cols x 32 k)
  char* const H1 = smem;          // 64KB panel (16 k-tiles)
  char* const H2 = smem;          // 32KB panel (8 k-tiles)

  const unsigned cB = (unsigned)(l7 ^ rl8);   // stored-chunk index for B staging lanes

  // frag-read offsets (paired-row bf16 k-tiles; slot = (((lm&1)<<2)+quad) ^ (lm>>1))
  const unsigned sl16 = (unsigned)(((((lm & 1) << 2) + quad) ^ (lm >> 1)) << 4);
  unsigned afoff[2];
#pragma unroll
  for (int tm = 0; tm < 2; tm++) afoff[tm] = (unsigned)((16 * wm + 8 * tm + (lm >> 1)) * 128) + sl16;
  unsigned bf1off[4];
#pragma unroll
  for (int tn = 0; tn < 4; tn++) bf1off[tn] = (unsigned)((wn * 32 + 8 * tn + (lm >> 1)) * 128) + sl16;

  // ---- A staging (phase 1): row mrow = 4*wid+quad; lane covers k = 2*lm, 2*lm+1
  const int mrow = 4 * wid + quad;
  const char* a1g = (const char*)x + (size_t)(rowg0 + (unsigned)mrow) * 3072 + (size_t)lm * 8;
  const unsigned a1d = (unsigned)(mrow >> 1) * 128u +
                       ((((unsigned)(mrow & 1) * 4u + ((unsigned)lm >> 2)) ^ ((unsigned)(mrow >> 1) & 7u)) << 4) +
                       ((unsigned)lm & 3u) * 4u;

  // ---- B1 staging (32KB/step = 2 gld16 per wave); linear LDS dst, swizzled global src
  unsigned b1s[2], b1d[2];
#pragma unroll
  for (int j = 0; j < 2; j++) {
    unsigned rr = (unsigned)(wid + 16 * j);                 // LDS-row group 0..31
    unsigned N_ = 16u * rr + 2u * (unsigned)rl8 + (cB >> 2);
    b1s[j] = N_ * 1536u + (cB & 3u) * 16u;                  // + step*64
    b1d[j] = rr * 1024u + (unsigned)lane * 16u;
  }

  // ================= phase 1: (64x768 fp32 -> bf16) @ zT1 -> 64x512, 24 steps =================
  float ss = 0.f;
  {
    float2 p0 = *(const float2*)a1g;
    ss += stage_a2(p0, A1 + a1d);                           // tile 0 -> buf0
  }
  float2 pA = *(const float2*)(a1g + 128);                  // tile 1 in flight
  gld16((const char*)zt1 + b1s[0], B1 + b1d[0]);
  gld16((const char*)zt1 + b1s[1], B1 + b1d[1]);

  ffrag4 acc1[2][4];
#pragma unroll
  for (int a = 0; a < 2; a++)
#pragma unroll
    for (int b = 0; b < 4; b++) acc1[a][b] = (ffrag4){0.f, 0.f, 0.f, 0.f};

  for (int k = 0; k < 24; k++) {
    __syncthreads();  // drains staging of tile k; prior readers of nxt done
    char* curA = A1 + (k & 1) * 4096;
    char* curB = B1 + (k & 1) * 32768;
    if (k < 23) {
      char* nA = A1 + ((k + 1) & 1) * 4096;
      char* nB = B1 + ((k + 1) & 1) * 32768;
      unsigned adv = (unsigned)(k + 1) * 64u;
      gld16((const char*)zt1 + b1s[0] + adv, nB + b1d[0]);
      gld16((const char*)zt1 + b1s[1] + adv, nB + b1d[1]);
      ss += stage_a2(pA, nA + a1d);
      if (k < 22) pA = *(const float2*)(a1g + (size_t)(k + 2) * 128);
    }
    bfrag8 a0 = *(const bfrag8*)(curA + afoff[0]);
    bfrag8 a1f = *(const bfrag8*)(curA + afoff[1]);
#pragma unroll
    for (int tn = 0; tn < 4; tn++) {
      bfrag8 bf = *(const bfrag8*)(curB + bf1off[tn]);
      acc1[0][tn] = __builtin_amdgcn_mfma_f32_16x16x32_bf16(a0, bf, acc1[0][tn], 0, 0, 0);
      acc1[1][tn] = __builtin_amdgcn_mfma_f32_16x16x32_bf16(a1f, bf, acc1[1][tn], 0, 0, 0);
    }
  }

  // ---- epilogue 1 ----
  __syncthreads();  // all phase-1 LDS reads done; A1/B1 dead

  // lambda0: reduce ss over the 16 lanes sharing a row (each x element counted exactly once)
  ss += __shfl_xor(ss, 1); ss += __shfl_xor(ss, 2);
  ss += __shfl_xor(ss, 4); ss += __shfl_xor(ss, 8);
  if (lm == 0) lamS[mrow] = 2.f / (1.f - CURV * ss);
  if (t < 64) { sums[0][t] = 0.f; sums[1][t] = 0.f; }
  __syncthreads();  // lamS/sums visible

  const float cs = sqrtf(CURV), inv_cs = 1.f / cs;
  poly_w<4>(acc1, st1, wn, lm, wm, quad, lamS, cs, inv_cs);
  reduce_rows<4, false>(acc1, nullptr, lm, wm, quad, sums);
  __syncthreads();
  if (t < 64) {
    float sw2 = sums[0][t], swp2 = sums[1][t];
    float den = 1.f + sqrtf(1.f + CURV * sw2);
    float nn = fmaxf(sqrtf(sw2) / den, EPSF);
    float al = atanhf(fminf(cs * nn, 1.f - 1e-7f)) / (cs * nn);
    float vn = fmaxf(al * sqrtf(swp2) / den, EPSF);
    float be = tanhf(cs * vn) / (cs * vn);
    float gam = al * be / den;
    gamS[t] = gam;
    lamS[t] = 2.f / (1.f - CURV * gam * gam * swp2);
    sums[0][t] = 0.f; sums[1][t] = 0.f;   // pre-zero for phase 2
  }
  __syncthreads();
  panel_write<4>(acc1, H1, lm, wm, wn, quad, gamS);  // H1 overlays dead A1/B1
  __syncthreads();  // H1 visible

  // ================= phase 2: h1(64x512) @ zT2 -> 64x256; NO barriers in loop ==============
  // B streamed from global: lane needs zT2[col=32*wn+16*tn+lm][k=kt*32+8*quad..+8) = 16B
  ffrag4 acc2[2][2];
#pragma unroll
  for (int a = 0; a < 2; a++)
#pragma unroll
    for (int b = 0; b < 2; b++) acc2[a][b] = (ffrag4){0.f, 0.f, 0.f, 0.f};

  const char* b2base = (const char*)zt2 + (size_t)(32 * wn + lm) * 1024 + (size_t)quad * 16;
#pragma unroll 4
  for (int kt = 0; kt < 16; kt++) {
    bfrag8 b0 = *(const bfrag8*)(b2base + kt * 64);
    bfrag8 b1v = *(const bfrag8*)(b2base + 16384 + kt * 64);   // +16 cols
    bfrag8 a0 = *(const bfrag8*)(H1 + kt * 4096 + afoff[0]);
    bfrag8 a1f = *(const bfrag8*)(H1 + kt * 4096 + afoff[1]);
    acc2[0][0] = __builtin_amdgcn_mfma_f32_16x16x32_bf16(a0,  b0,  acc2[0][0], 0, 0, 0);
    acc2[0][1] = __builtin_amdgcn_mfma_f32_16x16x32_bf16(a0,  b1v, acc2[0][1], 0, 0, 0);
    acc2[1][0] = __builtin_amdgcn_mfma_f32_16x16x32_bf16(a1f, b0,  acc2[1][0], 0, 0, 0);
    acc2[1][1] = __builtin_amdgcn_mfma_f32_16x16x32_bf16(a1f, b1v, acc2[1][1], 0, 0, 0);
  }
  __syncthreads();  // all H1 reads done (H2 will overlay)

  // ---- epilogue 2 ----
  poly_w<2>(acc2, st2, wn, lm, wm, quad, lamS, cs, inv_cs);
  reduce_rows<2, false>(acc2, nullptr, lm, wm, quad, sums);
  __syncthreads();
  if (t < 64) {
    float sw2 = sums[0][t], swp2 = sums[1][t];
    float den = 1.f + sqrtf(1.f + CURV * sw2);
    float nn = fmaxf(sqrtf(sw2) / den, EPSF);
    float al = atanhf(fminf(cs * nn, 1.f - 1e-7f)) / (cs * nn);
    float vn = fmaxf(al * sqrtf(swp2) / den, EPSF);
    float be = tanhf(cs * vn) / (cs * vn);
    float gam = al * be / den;
    gamS[t] = gam;
    lamS[t] = 2.f / (1.f - CURV * gam * gam * swp2);
    sums[0][t] = 0.f; sums[1][t] = 0.f; sums[2][t] = 0.f;  // pre-zero for phase 3
  }
  __syncthreads();
  panel_write<2>(acc2, H2, lm, wm, wn, quad, gamS);  // H2 overlays dead H1 head
  __syncthreads();  // H2 visible

  // ================= phase 3: h2(64x256) @ zT3 -> 64x128 (+L4 dot); NO barriers ============
  ffrag4 acc3[2][1];
  acc3[0][0] = (ffrag4){0.f, 0.f, 0.f, 0.f};
  acc3[1][0] = (ffrag4){0.f, 0.f, 0.f, 0.f};
  float z4v[1] = { z4[wn * 16 + lm] };

  const char* b3base = (const char*)zt3 + (size_t)(16 * wn + lm) * 512 + (size_t)quad * 16;
#pragma unroll 4
  for (int kt = 0; kt < 8; kt++) {
    bfrag8 bf = *(const bfrag8*)(b3base + kt * 64);
    bfrag8 a0 = *(const bfrag8*)(H2 + kt * 4096 + afoff[0]);
    bfrag8 a1f = *(const bfrag8*)(H2 + kt * 4096 + afoff[1]);
    acc3[0][0] = __builtin_amdgcn_mfma_f32_16x16x32_bf16(a0,  bf, acc3[0][0], 0, 0, 0);
    acc3[1][0] = __builtin_amdgcn_mfma_f32_16x16x32_bf16(a1f, bf, acc3[1][0], 0, 0, 0);
  }

  poly_w<1>(acc3, st3, wn, lm, wm, quad, lamS, cs, inv_cs);
  reduce_rows<1, true>(acc3, z4v, lm, wm, quad, sums);
  __syncthreads();
  if (t < 64) {
    float sw2 = sums[0][t], swp2 = sums[1][t];
    float den = 1.f + sqrtf(1.f + CURV * sw2);
    float nn = fmaxf(sqrtf(sw2) / den, EPSF);
    float al = atanhf(fminf(cs * nn, 1.f - 1e-7f)) / (cs * nn);
    float vn = fmaxf(al * sqrtf(swp2) / den, EPSF);
    float be = tanhf(cs * vn) / (cs * vn);
    float gam = al * be / den;
    float s = gam * sums[2][t];
    float lamh = 2.f / (1.f - CURV * gam * gam * swp2);
    float g = cs * lamh * s * st4[1] - (lamh - 1.f) * st4[2];
    float q = g * g;
    float u = g * (1.f - q * (1.f / 6.f) + q * q * 0.075f - q * q * q * 0.044642857f);
    float d1 = st4[0] * u;
    float S = 2.f * g * sqrtf(1.f + q);
    float Ch = 1.f + 2.f * q;
    float w = (S * (1.f + 0.5f * d1 * d1) + Ch * d1) * inv_cs;
    outF[rowg0 + t] = w / (1.f + sqrtf(1.f + CURV * w * w));
  }
}

extern "C" void kernel_launch(void* const* d_in, const int* in_sizes, int n_in,
                              void* d_out, int out_size, void* d_ws, size_t ws_size,
                              hipStream_t stream) {
  const float* x  = (const float*)d_in[0];
  const float* z1 = (const float*)d_in[1];
  const float* b1 = (const float*)d_in[2];
  const float* z2 = (const float*)d_in[3];
  const float* b2 = (const float*)d_in[4];
  const float* z3 = (const float*)d_in[5];
  const float* b3 = (const float*)d_in[6];
  const float* z4 = (const float*)d_in[7];
  const float* b4 = (const float*)d_in[8];

  char* ws = (char*)d_ws; size_t off = 0;
  auto carve = [&](size_t b) { char* p = ws + off; off += (b + 255) & ~(size_t)255; return p; };
  unsigned short* zT1 = (unsigned short*)carve(512 * 768 * 2);
  unsigned short* zT2 = (unsigned short*)carve(256 * 512 * 2);
  unsigned short* zT3 = (unsigned short*)carve(128 * 256 * 2);
  unsigned short* zT4 = (unsigned short*)carve(128 * 2);
  float* st1 = (float*)carve(512 * 4 * 4);
  float* st2 = (float*)carve(256 * 4 * 4);
  float* st3 = (float*)carve(128 * 4 * 4);
  float* st4 = (float*)carve(4 * 4);

  prep_tiled<<<15, 256, 0, stream>>>(z1, b1, z2, b2, z3, b3, z4, b4,
                                     zT1, st1, zT2, st2, zT3, st3, zT4, st4);
  fused_mlp<<<1024, 1024, 0, stream>>>(x, zT1, st1, zT2, st2, zT3, st3, z4, st4, (float*)d_out);
}

// Round 6
// 428.990 us; speedup vs baseline: 1.1808x; 1.1808x over previous
//
#include <hip/hip_runtime.h>

#define CURV 2.3026f
#define EPSF 1e-15f

typedef __attribute__((ext_vector_type(8))) short bfrag8;
typedef __attribute__((ext_vector_type(4))) float ffrag4;

static __device__ __forceinline__ unsigned short f2bf(float f) {
  unsigned u = __builtin_bit_cast(unsigned, f);
  u += 0x7fffu + ((u >> 16) & 1u);
  return (unsigned short)(u >> 16);
}

// async global->LDS, 16B per lane; LDS dest = wave-uniform base + lane*16 (global side is per-lane)
static __device__ __forceinline__ void gld16(const void* g, void* l) {
  unsigned lo = (unsigned)(unsigned long long)l;
  __builtin_amdgcn_global_load_lds(
      (const __attribute__((address_space(1))) unsigned int*)g,
      (__attribute__((address_space(3))) unsigned int*)lo, 16, 0, 0);
}

// ---- prep stage A: one 64x64 tile per block, coalesced transpose + atomicAdd col-ss partials ----
// grid 137: [0,96) L1 (12kt x 8ct), [96,128) L2 (8x4), [128,136) L3 (4x2), 136 L4 vector
__global__ void prep_transpose(const float* __restrict__ z1, const float* __restrict__ z2,
                               const float* __restrict__ z3, const float* __restrict__ z4,
                               unsigned short* __restrict__ zT1, unsigned short* __restrict__ zT2,
                               unsigned short* __restrict__ zT3, unsigned short* __restrict__ zT4,
                               float* __restrict__ ssA) {
  int b = blockIdx.x, t = threadIdx.x;  // 256 threads
  const float* z; unsigned short* zT; int K, N, kt, ct, sbase;
  if (b < 96)       { z = z1; zT = zT1; K = 768; N = 512; kt = b / 8;  ct = b & 7;        sbase = 0; }
  else if (b < 128) { int bb = b - 96;  z = z2; zT = zT2; K = 512; N = 256; kt = bb / 4; ct = bb & 3; sbase = 512; }
  else if (b < 136) { int bb = b - 128; z = z3; zT = zT3; K = 256; N = 128; kt = bb / 2; ct = bb & 1; sbase = 768; }
  else {
    float v = (t < 128) ? z4[t] : 0.f;
    if (t < 128) zT4[t] = f2bf(v);
    float ssl = v * v;
    for (int m = 1; m <= 32; m <<= 1) ssl += __shfl_xor(ssl, m);
    __shared__ float red4[4];
    if ((t & 63) == 0) red4[t >> 6] = ssl;
    __syncthreads();
    if (t == 0) atomicAdd(&ssA[896], red4[0] + red4[1] + red4[2] + red4[3]);
    return;
  }
  __shared__ unsigned short tile[64 * 72];
  __shared__ float red[4][64];
  const int c = t & 63, rq = t >> 6;
  const int n0 = ct * 64, k0 = kt * 64;
  float ssl = 0.f;
#pragma unroll
  for (int p = 0; p < 16; p++) {
    int k = k0 + 4 * p + rq;
    float v = z[(size_t)k * N + n0 + c];      // 64 consecutive cols: coalesced
    ssl += v * v;
    tile[c * 72 + 4 * p + rq] = f2bf(v);      // transposed store
  }
  red[rq][c] = ssl;
  __syncthreads();
  {  // write 64 rows x 128B coalesced; thread: row = t>>2, 32B segment = t&3
    int wr = t >> 2, seg = t & 3;
    const unsigned long long* src = (const unsigned long long*)(tile + wr * 72 + seg * 16);
    unsigned long long* dst = (unsigned long long*)(zT + (size_t)(n0 + wr) * K + k0 + seg * 16);
    dst[0] = src[0]; dst[1] = src[1]; dst[2] = src[2]; dst[3] = src[3];
  }
  if (t < 64) atomicAdd(&ssA[sbase + n0 + t], red[0][t] + red[1][t] + red[2][t] + red[3][t]);
}

// ---- prep stage B: per-col stats {2(zn-1), cosh(tcr)/zn, sinh(tcr), 0} from accumulated ss ----
__global__ void prep_stats(const float* __restrict__ ssA,
                           const float* __restrict__ r1, const float* __restrict__ r2,
                           const float* __restrict__ r3, const float* __restrict__ r4,
                           float* __restrict__ st1, float* __restrict__ st2,
                           float* __restrict__ st3, float* __restrict__ st4) {
  int i = blockIdx.x * 512 + threadIdx.x;
  if (i >= 897) return;
  const float* rv; float* st; int n;
  if (i < 512)      { rv = r1; st = st1; n = i; }
  else if (i < 768) { rv = r2; st = st2; n = i - 512; }
  else if (i < 896) { rv = r3; st = st3; n = i - 768; }
  else              { rv = r4; st = st4; n = 0; }
  float cs = sqrtf(CURV);
  float zn = fmaxf(sqrtf(ssA[i]), EPSF);
  float tc = 2.f * cs * rv[n];
  st[4 * n + 0] = 2.f * (zn - 1.f);
  st[4 * n + 1] = coshf(tc) / zn;
  st[4 * n + 2] = sinhf(tc);
  st[4 * n + 3] = 0.f;
}

// s -> w via polynomial sinh(2*zn*asinh(g)) expansion (|g|<~0.35, |delta|<~0.16); in place on acc
template<int NT>
static __device__ __forceinline__ void poly_w(ffrag4 (&acc)[2][NT], const float* __restrict__ stats,
                                              int wn, int lm, int wm, int quad,
                                              const float* lamP, float cs, float inv_cs) {
#pragma unroll
  for (int tn = 0; tn < NT; tn++) {
    float4 st = *(const float4*)(stats + 4 * (wn * (16 * NT) + 16 * tn + lm));
    float dl = st.x, chozn = st.y, sh = st.z;
#pragma unroll
    for (int tm = 0; tm < 2; tm++) {
#pragma unroll
      for (int rg = 0; rg < 4; rg++) {
        float lam = lamP[32 * wm + 16 * tm + 4 * quad + rg];
        float g = cs * lam * acc[tm][tn][rg] * chozn - (lam - 1.f) * sh;
        float q = g * g;
        float u = g * (1.f - q * (1.f / 6.f) + q * q * 0.075f - q * q * q * 0.044642857f);
        float d1 = dl * u;
        float S = 2.f * g * sqrtf(1.f + q);
        float Ch = 1.f + 2.f * q;
        acc[tm][tn][rg] = (S * (1.f + 0.5f * d1 * d1) + Ch * d1) * inv_cs;
      }
    }
  }
}

// row reductions: sum w^2, sum relu(w)^2, (L4) sum relu(w)*z4
template<int NT, bool L4>
static __device__ __forceinline__ void reduce_rows(ffrag4 (&acc)[2][NT], const float* z4v,
                                                   int lm, int wm, int quad, float (*sums_)[64]) {
#pragma unroll
  for (int tm = 0; tm < 2; tm++) {
#pragma unroll
    for (int rg = 0; rg < 4; rg++) {
      float s2 = 0.f, sp2 = 0.f, s4 = 0.f;
#pragma unroll
      for (int tn = 0; tn < NT; tn++) {
        float w = acc[tm][tn][rg];
        s2 += w * w;
        float wp = fmaxf(w, 0.f);
        sp2 += wp * wp;
        if (L4) s4 += wp * z4v[tn];
      }
#pragma unroll
      for (int m = 1; m <= 8; m <<= 1) {
        s2 += __shfl_xor(s2, m, 16);
        sp2 += __shfl_xor(sp2, m, 16);
        if (L4) s4 += __shfl_xor(s4, m, 16);
      }
      if (lm == 0) {
        int row = 32 * wm + 16 * tm + 4 * quad + rg;
        atomicAdd(&sums_[0][row], s2);
        atomicAdd(&sums_[1][row], sp2);
        if (L4) atomicAdd(&sums_[2][row], s4);
      }
    }
  }
}

// write h = gam*relu(w) as bf16 into a panel of 4KB k-tiles in the paired-row swizzled layout:
// data (row r, 16B-chunk c' in [0,4)) of k-tile kt at kt*4096 + (r>>1)*128 + ((4*(r&1)+c')^((r>>1)&7))*16
template<int NT>
static __device__ __forceinline__ void panel_write(ffrag4 (&acc)[2][NT], char* panel,
                                                   int lm, int wm, int wn, int quad,
                                                   const float* gamP) {
#pragma unroll
  for (int tm = 0; tm < 2; tm++)
#pragma unroll
    for (int rg = 0; rg < 4; rg++) {
      const int r = 32 * wm + 16 * tm + 4 * quad + rg;
      const float gam = gamP[r];
      const unsigned rb = (unsigned)((r >> 1) * 128);
      const unsigned rx = (unsigned)((r >> 1) & 7);
      const unsigned c0 = (unsigned)((r & 1) * 4);
#pragma unroll
      for (int tn = 0; tn < NT; tn++) {
        const int col = wn * (16 * NT) + 16 * tn + lm;
        const unsigned ad = (unsigned)((col >> 5) * 4096) + rb +
                            (((c0 + (unsigned)((col >> 3) & 3)) ^ rx) << 4) +
                            (unsigned)((col & 7) * 2);
        *(unsigned short*)(panel + ad) = f2bf(gam * fmaxf(acc[tm][tn][rg], 0.f));
      }
    }
}

// convert 4 fp32 -> 4 bf16, ds_write_b64 into paired-row layout; returns sum of squares
static __device__ __forceinline__ float stage_a4(float4 f, char* p) {
  ushort4 h; h.x = f2bf(f.x); h.y = f2bf(f.y); h.z = f2bf(f.z); h.w = f2bf(f.w);
  *(ushort4*)p = h;
  return f.x * f.x + f.y * f.y + f.z * f.z + f.w * f.w;
}

// ---- fully fused 4-layer Poincare MLP: 64 rows/block, 8 waves (2M x 4N), 512 threads.
// __launch_bounds__(512,4) -> 128 VGPR cap (no spill; R5's (1024,8)=64-cap spilled 90MB scratch).
// LDS 72KB + extras -> 2 blocks/CU = two INDEPENDENT barrier groups: one block's vmcnt/barrier
// drain overlaps the other's MFMA. Phase 1: BK=32, A reg-staged, B1 gld16 dbuf, 24 steps.
// Phases 2/3: A from LDS h-panels, B streamed from L2-warm global, zero barriers in k-loops.
//   ph1: A1 dbuf [0,8K) + B1 dbuf [8K,72K);  ph2: H1 [0,64K);  ph3: H2 [0,32K)
__launch_bounds__(512, 4)
__global__ void fused_mlp(const float* __restrict__ x,
                          const unsigned short* __restrict__ zt1, const float* __restrict__ st1,
                          const unsigned short* __restrict__ zt2, const float* __restrict__ st2,
                          const unsigned short* __restrict__ zt3, const float* __restrict__ st3,
                          const float* __restrict__ z4, const float* __restrict__ st4,
                          float* __restrict__ outF) {
  __shared__ __align__(16) char smem[73728];
  __shared__ float lamS[64];
  __shared__ float gamS[64];
  __shared__ float sums[3][64];

  const int t = threadIdx.x;
  const int wid = t >> 6, lane = t & 63;          // 8 waves
  const int wm = wid >> 2, wn = wid & 3;          // 2M x 4N
  const int lm = lane & 15, quad = lane >> 4;
  const int l7 = lane & 7, rl8 = lane >> 3;
  const unsigned rowg0 = blockIdx.x * 64u;

  char* const A1 = smem;          // 2 x 4KB bf16 x-tiles (64 rows x 32 k)
  char* const B1 = smem + 8192;   // 2 x 32KB (512 cols x 32 k)
  char* const H1 = smem;          // 64KB panel (16 k-tiles)
  char* const H2 = smem;          // 32KB panel (8 k-tiles)

  const unsigned cB = (unsigned)(l7 ^ rl8);   // stored-chunk index for B staging lanes

  // frag-read offsets (paired-row bf16 k-tiles; slot = (((lm&1)<<2)+quad) ^ (lm>>1))
  const unsigned sl16 = (unsigned)(((((lm & 1) << 2) + quad) ^ (lm >> 1)) << 4);
  unsigned afoff[2];
#pragma unroll
  for (int tm = 0; tm < 2; tm++) afoff[tm] = (unsigned)((16 * wm + 8 * tm + (lm >> 1)) * 128) + sl16;
  unsigned bf1off[8];
#pragma unroll
  for (int tn = 0; tn < 8; tn++) bf1off[tn] = (unsigned)((wn * 64 + 8 * tn + (lm >> 1)) * 128) + sl16;

  // ---- A staging (phase 1): row mrow = 8*wid+rl8; lane covers k = 4*l7..4*l7+3
  const int mrow = 8 * wid + rl8;
  const char* a1g = (const char*)x + (size_t)(rowg0 + (unsigned)mrow) * 3072 + (size_t)l7 * 16;
  const unsigned a1d = (unsigned)(mrow >> 1) * 128u +
                       ((((unsigned)(mrow & 1) * 4u + ((unsigned)l7 >> 1)) ^ ((unsigned)(mrow >> 1) & 7u)) << 4) +
                       ((unsigned)l7 & 1u) * 8u;

  // ---- B1 staging (32KB/step = 4 gld16 per wave); linear LDS dst, swizzled global src
  unsigned b1s[4], b1d[4];
#pragma unroll
  for (int j = 0; j < 4; j++) {
    unsigned rr = (unsigned)(wid + 8 * j);                  // LDS 1KB-group 0..31
    unsigned N_ = 16u * rr + 2u * (unsigned)rl8 + (cB >> 2);
    b1s[j] = N_ * 1536u + (cB & 3u) * 16u;                  // + step*64
    b1d[j] = rr * 1024u + (unsigned)lane * 16u;
  }

  // ================= phase 1: (64x768 fp32 -> bf16) @ zT1 -> 64x512, 24 steps =================
  float ss = 0.f;
  {
    float4 p0 = *(const float4*)a1g;
    ss += stage_a4(p0, A1 + a1d);                           // tile 0 -> buf0
  }
  float4 pA = *(const float4*)(a1g + 128);                  // tile 1 in flight
#pragma unroll
  for (int j = 0; j < 4; j++) gld16((const char*)zt1 + b1s[j], B1 + b1d[j]);

  ffrag4 acc1[2][8];
#pragma unroll
  for (int a = 0; a < 2; a++)
#pragma unroll
    for (int b = 0; b < 8; b++) acc1[a][b] = (ffrag4){0.f, 0.f, 0.f, 0.f};

  for (int k = 0; k < 24; k++) {
    __syncthreads();  // drains staging of tile k; prior readers of nxt done
    char* curA = A1 + (k & 1) * 4096;
    char* curB = B1 + (k & 1) * 32768;
    if (k < 23) {
      char* nA = A1 + ((k + 1) & 1) * 4096;
      char* nB = B1 + ((k + 1) & 1) * 32768;
      unsigned adv = (unsigned)(k + 1) * 64u;
#pragma unroll
      for (int j = 0; j < 4; j++) gld16((const char*)zt1 + b1s[j] + adv, nB + b1d[j]);
      ss += stage_a4(pA, nA + a1d);
      if (k < 22) pA = *(const float4*)(a1g + (size_t)(k + 2) * 128);
    }
    bfrag8 a0 = *(const bfrag8*)(curA + afoff[0]);
    bfrag8 a1f = *(const bfrag8*)(curA + afoff[1]);
#pragma unroll
    for (int tn = 0; tn < 8; tn++) {
      bfrag8 bf = *(const bfrag8*)(curB + bf1off[tn]);
      acc1[0][tn] = __builtin_amdgcn_mfma_f32_16x16x32_bf16(a0, bf, acc1[0][tn], 0, 0, 0);
      acc1[1][tn] = __builtin_amdgcn_mfma_f32_16x16x32_bf16(a1f, bf, acc1[1][tn], 0, 0, 0);
    }
  }

  // ---- epilogue 1 ----
  __syncthreads();  // all phase-1 LDS reads done; A1/B1 dead

  // lambda0: reduce ss over the 8 lanes sharing a row (each x element counted exactly once)
  ss += __shfl_xor(ss, 1); ss += __shfl_xor(ss, 2); ss += __shfl_xor(ss, 4);
  if (l7 == 0) lamS[mrow] = 2.f / (1.f - CURV * ss);
  if (t < 64) { sums[0][t] = 0.f; sums[1][t] = 0.f; }
  __syncthreads();  // lamS/sums visible

  const float cs = sqrtf(CURV), inv_cs = 1.f / cs;
  poly_w<8>(acc1, st1, wn, lm, wm, quad, lamS, cs, inv_cs);
  reduce_rows<8, false>(acc1, nullptr, lm, wm, quad, sums);
  __syncthreads();
  if (t < 64) {
    float sw2 = sums[0][t], swp2 = sums[1][t];
    float den = 1.f + sqrtf(1.f + CURV * sw2);
    float nn = fmaxf(sqrtf(sw2) / den, EPSF);
    float al = atanhf(fminf(cs * nn, 1.f - 1e-7f)) / (cs * nn);
    float vn = fmaxf(al * sqrtf(swp2) / den, EPSF);
    float be = tanhf(cs * vn) / (cs * vn);
    float gam = al * be / den;
    gamS[t] = gam;
    lamS[t] = 2.f / (1.f - CURV * gam * gam * swp2);
    sums[0][t] = 0.f; sums[1][t] = 0.f;   // pre-zero for phase 2
  }
  __syncthreads();
  panel_write<8>(acc1, H1, lm, wm, wn, quad, gamS);  // H1 overlays dead A1/B1
  __syncthreads();  // H1 visible

  // ================= phase 2: h1(64x512) @ zT2 -> 64x256; NO barriers in loop ==============
  // B streamed from global: lane needs zT2[col=64*wn+16*tn+lm][k=kt*32+8*quad..+8) = 16B
  ffrag4 acc2[2][4];
#pragma unroll
  for (int a = 0; a < 2; a++)
#pragma unroll
    for (int b = 0; b < 4; b++) acc2[a][b] = (ffrag4){0.f, 0.f, 0.f, 0.f};

  const char* b2base = (const char*)zt2 + (size_t)(64 * wn + lm) * 1024 + (size_t)quad * 16;
#pragma unroll 4
  for (int kt = 0; kt < 16; kt++) {
    bfrag8 a0 = *(const bfrag8*)(H1 + kt * 4096 + afoff[0]);
    bfrag8 a1f = *(const bfrag8*)(H1 + kt * 4096 + afoff[1]);
#pragma unroll
    for (int tn = 0; tn < 4; tn++) {
      bfrag8 bv = *(const bfrag8*)(b2base + (size_t)tn * 16384 + kt * 64);
      acc2[0][tn] = __builtin_amdgcn_mfma_f32_16x16x32_bf16(a0,  bv, acc2[0][tn], 0, 0, 0);
      acc2[1][tn] = __builtin_amdgcn_mfma_f32_16x16x32_bf16(a1f, bv, acc2[1][tn], 0, 0, 0);
    }
  }
  __syncthreads();  // all H1 reads done (H2 will overlay)

  // ---- epilogue 2 ----
  poly_w<4>(acc2, st2, wn, lm, wm, quad, lamS, cs, inv_cs);
  reduce_rows<4, false>(acc2, nullptr, lm, wm, quad, sums);
  __syncthreads();
  if (t < 64) {
    float sw2 = sums[0][t], swp2 = sums[1][t];
    float den = 1.f + sqrtf(1.f + CURV * sw2);
    float nn = fmaxf(sqrtf(sw2) / den, EPSF);
    float al = atanhf(fminf(cs * nn, 1.f - 1e-7f)) / (cs * nn);
    float vn = fmaxf(al * sqrtf(swp2) / den, EPSF);
    float be = tanhf(cs * vn) / (cs * vn);
    float gam = al * be / den;
    gamS[t] = gam;
    lamS[t] = 2.f / (1.f - CURV * gam * gam * swp2);
    sums[0][t] = 0.f; sums[1][t] = 0.f; sums[2][t] = 0.f;  // pre-zero for phase 3
  }
  __syncthreads();
  panel_write<4>(acc2, H2, lm, wm, wn, quad, gamS);  // H2 overlays dead H1 head
  __syncthreads();  // H2 visible

  // ================= phase 3: h2(64x256) @ zT3 -> 64x128 (+L4 dot); NO barriers ============
  ffrag4 acc3[2][2];
#pragma unroll
  for (int a = 0; a < 2; a++)
#pragma unroll
    for (int b = 0; b < 2; b++) acc3[a][b] = (ffrag4){0.f, 0.f, 0.f, 0.f};
  float z4v[2] = { z4[32 * wn + lm], z4[32 * wn + 16 + lm] };

  const char* b3base = (const char*)zt3 + (size_t)(32 * wn + lm) * 512 + (size_t)quad * 16;
#pragma unroll 4
  for (int kt = 0; kt < 8; kt++) {
    bfrag8 a0 = *(const bfrag8*)(H2 + kt * 4096 + afoff[0]);
    bfrag8 a1f = *(const bfrag8*)(H2 + kt * 4096 + afoff[1]);
#pragma unroll
    for (int tn = 0; tn < 2; tn++) {
      bfrag8 bv = *(const bfrag8*)(b3base + (size_t)tn * 8192 + kt * 64);
      acc3[0][tn] = __builtin_amdgcn_mfma_f32_16x16x32_bf16(a0,  bv, acc3[0][tn], 0, 0, 0);
      acc3[1][tn] = __builtin_amdgcn_mfma_f32_16x16x32_bf16(a1f, bv, acc3[1][tn], 0, 0, 0);
    }
  }

  poly_w<2>(acc3, st3, wn, lm, wm, quad, lamS, cs, inv_cs);
  reduce_rows<2, true>(acc3, z4v, lm, wm, quad, sums);
  __syncthreads();
  if (t < 64) {
    float sw2 = sums[0][t], swp2 = sums[1][t];
    float den = 1.f + sqrtf(1.f + CURV * sw2);
    float nn = fmaxf(sqrtf(sw2) / den, EPSF);
    float al = atanhf(fminf(cs * nn, 1.f - 1e-7f)) / (cs * nn);
    float vn = fmaxf(al * sqrtf(swp2) / den, EPSF);
    float be = tanhf(cs * vn) / (cs * vn);
    float gam = al * be / den;
    float s = gam * sums[2][t];
    float lamh = 2.f / (1.f - CURV * gam * gam * swp2);
    float g = cs * lamh * s * st4[1] - (lamh - 1.f) * st4[2];
    float q = g * g;
    float u = g * (1.f - q * (1.f / 6.f) + q * q * 0.075f - q * q * q * 0.044642857f);
    float d1 = st4[0] * u;
    float S = 2.f * g * sqrtf(1.f + q);
    float Ch = 1.f + 2.f * q;
    float w = (S * (1.f + 0.5f * d1 * d1) + Ch * d1) * inv_cs;
    outF[rowg0 + t] = w / (1.f + sqrtf(1.f + CURV * w * w));
  }
}

extern "C" void kernel_launch(void* const* d_in, const int* in_sizes, int n_in,
                              void* d_out, int out_size, void* d_ws, size_t ws_size,
                              hipStream_t stream) {
  const float* x  = (const float*)d_in[0];
  const float* z1 = (const float*)d_in[1];
  const float* b1 = (const float*)d_in[2];
  const float* z2 = (const float*)d_in[3];
  const float* b2 = (const float*)d_in[4];
  const float* z3 = (const float*)d_in[5];
  const float* b3 = (const float*)d_in[6];
  const float* z4 = (const float*)d_in[7];
  const float* b4 = (const float*)d_in[8];

  char* ws = (char*)d_ws; size_t off = 0;
  auto carve = [&](size_t b) { char* p = ws + off; off += (b + 255) & ~(size_t)255; return p; };
  unsigned short* zT1 = (unsigned short*)carve(512 * 768 * 2);
  unsigned short* zT2 = (unsigned short*)carve(256 * 512 * 2);
  unsigned short* zT3 = (unsigned short*)carve(128 * 256 * 2);
  unsigned short* zT4 = (unsigned short*)carve(128 * 2);
  float* st1 = (float*)carve(512 * 4 * 4);
  float* st2 = (float*)carve(256 * 4 * 4);
  float* st3 = (float*)carve(128 * 4 * 4);
  float* st4 = (float*)carve(4 * 4);
  float* ssA = (float*)carve(897 * 4);

  hipMemsetAsync(ssA, 0, 897 * 4, stream);
  prep_transpose<<<137, 256, 0, stream>>>(z1, z2, z3, z4, zT1, zT2, zT3, zT4, ssA);
  prep_stats<<<2, 512, 0, stream>>>(ssA, b1, b2, b3, b4, st1, st2, st3, st4);
  fused_mlp<<<1024, 512, 0, stream>>>(x, zT1, st1, zT2, st2, zT3, st3, z4, st4, (float*)d_out);
}